// Round 2
// baseline (1030.193 us; speedup 1.0000x reference)
//
#include <hip/hip_runtime.h>
#include <hip/hip_bf16.h>

#define B_ 128
#define L_ 1024
#define T_ 64

using short8 = __attribute__((ext_vector_type(8))) short;
using f32x4  = __attribute__((ext_vector_type(4))) float;

__device__ __forceinline__ unsigned short bfb(float x) {
  return __builtin_bit_cast(unsigned short, __float2bfloat16(x));
}
__device__ __forceinline__ float asf(unsigned u) { return __builtin_bit_cast(float, u); }
__device__ __forceinline__ float bf2f(unsigned short b) { return asf(((unsigned)b) << 16); }

// LDS P layout (bf16): P[m][k] at ushort idx = (k>>5)*512 + ((k>>3)&3)*128 + m*8 + (k&7)
// -> B-frag read (lane: n=m=L&15, k=32h+8q+d) is one contiguous 16B ds_read_b128 per h.
__device__ __forceinline__ int paddr(int k, int m) {
  return ((k >> 5) << 9) + (((k >> 3) & 3) << 7) + (m << 3) + (k & 7);
}

// ---------------- K1: F[token][tag] = exp(embed[x[token]] . W[:,tag] + b[tag]) (bf16)
__global__ __launch_bounds__(256) void k_emis(const int* __restrict__ x,
                                              const float* __restrict__ embed,
                                              const float* __restrict__ W,
                                              const float* __restrict__ bias,
                                              __hip_bfloat16* __restrict__ F) {
  __shared__ unsigned short Wsw[16384];  // W bf16, B-frag swizzled: 32 KB
  __shared__ float Tr[4][16][68];        // per-wave transpose buffer (padded rows)
  for (int e = threadIdx.x; e < 16384; e += 256) {
    int k = e >> 6, n = e & 63;  // W[k][n], e-linear -> coalesced fp32 reads
    int idx = ((k >> 5) << 11) + ((n >> 4) << 9) + (((k >> 3) & 3) << 7) + ((n & 15) << 3) + (k & 7);
    Wsw[idx] = bfb(W[e]);
  }
  __syncthreads();
  const int wv = threadIdx.x >> 6, L = threadIdx.x & 63, m = L & 15, q = L >> 4;
  const int tokbase = blockIdx.x * 64 + wv * 16;
  const float* erow = embed + (size_t)x[tokbase + m] * 256;  // A row = token (lane&15)
  f32x4 acc[4] = {{0.f, 0.f, 0.f, 0.f}, {0.f, 0.f, 0.f, 0.f},
                  {0.f, 0.f, 0.f, 0.f}, {0.f, 0.f, 0.f, 0.f}};
  for (int kk = 0; kk < 8; kk++) {
    float4 a0 = *(const float4*)(erow + 32 * kk + 8 * q);
    float4 a1 = *(const float4*)(erow + 32 * kk + 8 * q + 4);
    short8 af;
    af[0] = (short)bfb(a0.x); af[1] = (short)bfb(a0.y);
    af[2] = (short)bfb(a0.z); af[3] = (short)bfb(a0.w);
    af[4] = (short)bfb(a1.x); af[5] = (short)bfb(a1.y);
    af[6] = (short)bfb(a1.z); af[7] = (short)bfb(a1.w);
    const unsigned short* wp = &Wsw[kk * 2048 + q * 128 + m * 8];
#pragma unroll
    for (int t = 0; t < 4; t++) {
      short8 bf8 = *(const short8*)(wp + t * 512);
      acc[t] = __builtin_amdgcn_mfma_f32_16x16x32_bf16(af, bf8, acc[t], 0, 0, 0);
    }
  }
  // D layout: col(tag within tile)=lane&15, row(token within 16)=4q+reg
#pragma unroll
  for (int t = 0; t < 4; t++) {
    float bv = bias[16 * t + m];
#pragma unroll
    for (int r = 0; r < 4; r++) Tr[wv][4 * q + r][16 * t + m] = acc[t][r] + bv;
  }
  // same-wave LDS round-trip (DS pipe is in-order per wave; no barrier needed)
  const int tok = tokbase + (L >> 2), cb = (L & 3) * 16;
#pragma unroll
  for (int i = 0; i < 4; i++) {
    float4 v = *(const float4*)&Tr[wv][L >> 2][cb + 4 * i];
    unsigned lo = bfb(__expf(v.x)) | ((unsigned)bfb(__expf(v.y)) << 16);
    unsigned hi = bfb(__expf(v.z)) | ((unsigned)bfb(__expf(v.w)) << 16);
    *(uint2*)((unsigned short*)F + (size_t)tok * T_ + cb + 4 * i) = make_uint2(lo, hi);
  }
}

// ---------------- K2: CRF forward in probability domain, MFMA, 16 batches/wave ----
__global__ __launch_bounds__(64) void k_crf(const __hip_bfloat16* __restrict__ F,
                                            const float* __restrict__ trans,
                                            float* __restrict__ logz) {
  __shared__ unsigned short Pb[1024];  // P[16 m][64 k] bf16, swizzled
  const int w = blockIdx.x, L = threadIdx.x, m = L & 15, q = L >> 4;
  const unsigned short* Fu = (const unsigned short*)F + (size_t)(w * 16 + m) * (L_ * T_);
  // A = E^T: frag[t][h]: row i = 16t+m (new tag), k = 32h+8q+d (old tag); E=exp(trans)
  short8 Afr[4][2];
#pragma unroll
  for (int t = 0; t < 4; t++)
#pragma unroll
    for (int h = 0; h < 2; h++) {
      short8 a;
#pragma unroll
      for (int d = 0; d < 8; d++) {
        int k = 32 * h + 8 * q + d;
        a[d] = (short)bfb(__expf(trans[k * T_ + 16 * t + m]));
      }
      Afr[t][h] = a;
    }
  // P0[m][k] = exp(trans[START][k]) * F[m][0][k]
#pragma unroll
  for (int i = 0; i < 16; i++) {
    int k = q + 4 * i;
    Pb[paddr(k, m)] = bfb(__expf(trans[k]) * bf2f(Fu[k]));
  }
  // F prefetch ring, depth 4 (off the critical recursion chain)
  uint2 Fr[4][4];
#pragma unroll
  for (int l = 1; l <= 4; l++)
#pragma unroll
    for (int t = 0; t < 4; t++)
      Fr[l & 3][t] = *(const uint2*)(Fu + (size_t)l * T_ + 16 * t + 4 * q);
  float log_acc = 0.f;
  for (int l = 1; l < L_; l++) {
    // B = P^T: col = batch m = lane&15, k = 32h+8q+d  (one b128 per half)
    short8 b0 = *(const short8*)&Pb[q * 128 + m * 8];
    short8 b1 = *(const short8*)&Pb[512 + q * 128 + m * 8];
    f32x4 acc[4];
#pragma unroll
    for (int t = 0; t < 4; t++) {
      f32x4 z = {0.f, 0.f, 0.f, 0.f};
      z = __builtin_amdgcn_mfma_f32_16x16x32_bf16(Afr[t][0], b0, z, 0, 0, 0);
      acc[t] = __builtin_amdgcn_mfma_f32_16x16x32_bf16(Afr[t][1], b1, z, 0, 0, 0);
    }
    // D: col = batch m, row = new tag j = 16t+4q+r ; multiply by F[m][l][j]
    float v[4][4];
#pragma unroll
    for (int t = 0; t < 4; t++) {
      uint2 u = Fr[l & 3][t];
      v[t][0] = acc[t][0] * asf(u.x << 16);
      v[t][1] = acc[t][1] * asf(u.x & 0xffff0000u);
      v[t][2] = acc[t][2] * asf(u.y << 16);
      v[t][3] = acc[t][3] * asf(u.y & 0xffff0000u);
    }
    int lp = l + 4; if (lp > L_ - 1) lp = L_ - 1;
#pragma unroll
    for (int t = 0; t < 4; t++)
      Fr[l & 3][t] = *(const uint2*)(Fu + (size_t)lp * T_ + 16 * t + 4 * q);
    if ((l & 7) == 0) {  // renorm: scale rows to max 1, accumulate log
      float mx = v[0][0];
#pragma unroll
      for (int t = 0; t < 4; t++)
#pragma unroll
        for (int r = 0; r < 4; r++) mx = fmaxf(mx, v[t][r]);
      mx = fmaxf(mx, __shfl_xor(mx, 16));
      mx = fmaxf(mx, __shfl_xor(mx, 32));
      float rs = 1.0f / mx;
      log_acc -= __logf(rs);
#pragma unroll
      for (int t = 0; t < 4; t++)
#pragma unroll
        for (int r = 0; r < 4; r++) v[t][r] *= rs;
    }
#pragma unroll
    for (int t = 0; t < 4; t++) {  // pack 4 consecutive j -> one 8B LDS write
      unsigned lo = bfb(v[t][0]) | ((unsigned)bfb(v[t][1]) << 16);
      unsigned hi = bfb(v[t][2]) | ((unsigned)bfb(v[t][3]) << 16);
      int j0 = 16 * t + 4 * q;
      *(uint2*)&Pb[paddr(j0, m)] = make_uint2(lo, hi);
    }
  }
  // logz[m] = log_acc + log(sum_k P[m][k] * exp(trans[k][END]))
  float s = 0.f;
#pragma unroll
  for (int i = 0; i < 16; i++) {
    int k = q + 4 * i;
    s += bf2f(Pb[paddr(k, m)]) * __expf(trans[k * T_ + 1]);
  }
  s += __shfl_xor(s, 16);
  s += __shfl_xor(s, 32);
  if (q == 0) logz[w * 16 + L] = log_acc + __logf(s);
}

// ---------------- K3: gold path score per batch (emissions recovered via log F) ----
__global__ __launch_bounds__(256) void k_scores(const int* __restrict__ tags,
                                                const __hip_bfloat16* __restrict__ F,
                                                const float* __restrict__ trans,
                                                float* __restrict__ score) {
  const int b = blockIdx.x;
  const int* tg = tags + (size_t)b * L_;
  const unsigned short* Fu = (const unsigned short*)F + (size_t)b * (L_ * T_);
  float acc = 0.f;
  for (int l = threadIdx.x; l < L_; l += 256) {
    const int t = tg[l];
    acc += __logf(bf2f(Fu[(size_t)l * T_ + t]));
    if (l < L_ - 1) acc += trans[t * T_ + tg[l + 1]];
  }
#pragma unroll
  for (int off = 32; off > 0; off >>= 1) acc += __shfl_xor(acc, off);
  __shared__ float red[4];
  if ((threadIdx.x & 63) == 0) red[threadIdx.x >> 6] = acc;
  __syncthreads();
  if (threadIdx.x == 0) {
    float s = red[0] + red[1] + red[2] + red[3];
    s += trans[0 * T_ + tg[0]];
    s += trans[tg[L_ - 1] * T_ + 1];
    score[b] = s;
  }
}

// ---------------- K4: out = -sum_b (score_b - logz_b) ----------------
__global__ __launch_bounds__(128) void k_final(const float* __restrict__ score,
                                               const float* __restrict__ logz,
                                               float* __restrict__ out) {
  const int t = threadIdx.x;
  float v = score[t] - logz[t];
#pragma unroll
  for (int off = 32; off > 0; off >>= 1) v += __shfl_xor(v, off);
  __shared__ float r[2];
  if ((t & 63) == 0) r[t >> 6] = v;
  __syncthreads();
  if (t == 0) out[0] = -(r[0] + r[1]);
}

extern "C" void kernel_launch(void* const* d_in, const int* in_sizes, int n_in,
                              void* d_out, int out_size, void* d_ws, size_t ws_size,
                              hipStream_t stream) {
  const int* x = (const int*)d_in[0];
  const int* tags = (const int*)d_in[1];
  const float* embed = (const float*)d_in[3];
  const float* W = (const float*)d_in[4];
  const float* bias = (const float*)d_in[5];
  const float* trans = (const float*)d_in[6];

  char* ws = (char*)d_ws;
  __hip_bfloat16* F = (__hip_bfloat16*)ws;  // 16 MB
  float* logz = (float*)(ws + (size_t)B_ * L_ * T_ * sizeof(__hip_bfloat16));
  float* score = logz + B_;
  float* out = (float*)d_out;

  k_emis<<<(B_ * L_) / 64, 256, 0, stream>>>(x, embed, W, bias, F);
  k_crf<<<8, 64, 0, stream>>>(F, trans, logz);
  k_scores<<<B_, 256, 0, stream>>>(tags, F, trans, score);
  k_final<<<1, 128, 0, stream>>>(score, logz, out);
}

// Round 3
// 251.890 us; speedup vs baseline: 4.0899x; 4.0899x over previous
//
#include <hip/hip_runtime.h>
#include <hip/hip_bf16.h>

#define B_ 128
#define L_ 1024
#define T_ 64

using short8 = __attribute__((ext_vector_type(8))) short;
using f32x4  = __attribute__((ext_vector_type(4))) float;
using f32x16 = __attribute__((ext_vector_type(16))) float;

static __device__ __forceinline__ unsigned short bfb(float x) {
  return __builtin_bit_cast(unsigned short, __float2bfloat16(x));
}
static __device__ __forceinline__ float asf(unsigned u) { return __builtin_bit_cast(float, u); }
static __device__ __forceinline__ float bf2f(unsigned short b) { return asf(((unsigned)b) << 16); }
static __device__ __forceinline__ unsigned pk2(float lo, float hi) {
  return (unsigned)bfb(lo) | ((unsigned)bfb(hi) << 16);
}
static __device__ __forceinline__ unsigned sx32(unsigned v) {
  return (unsigned)__shfl_xor((int)v, 32);
}

// ---------- K0: expET[i][k] = exp(trans[k][i])  (bf16, A-operand table) ----------
__global__ __launch_bounds__(256) void k_prep(const float* __restrict__ trans,
                                              unsigned short* __restrict__ expET) {
  int t = blockIdx.x * 256 + threadIdx.x;  // 4096
  expET[t] = bfb(__expf(trans[(t & 63) * T_ + (t >> 6)]));
}

// ---------- K1: F[token][tag] = softmax_tag(embed[x]·W + b)  (bf16) ----------
__global__ __launch_bounds__(256) void k_emis(const int* __restrict__ x,
                                              const float* __restrict__ embed,
                                              const float* __restrict__ W,
                                              const float* __restrict__ bias,
                                              unsigned short* __restrict__ Fout) {
  const int L = threadIdx.x & 63, wv = threadIdx.x >> 6, m = L & 15, q = L >> 4;
  // B = W fragments, held in VGPRs (no LDS restage)
  short8 Wf[8][4];
#pragma unroll
  for (int kap = 0; kap < 8; kap++)
#pragma unroll
    for (int u = 0; u < 4; u++) {
      short8 w;
#pragma unroll
      for (int d = 0; d < 8; d++)
        w[d] = (short)bfb(W[(32 * kap + 8 * q + d) * T_ + 16 * u + m]);
      Wf[kap][u] = w;
    }
  const float bj0 = bias[m], bj1 = bias[16 + m], bj2 = bias[32 + m], bj3 = bias[48 + m];
  for (int it = 0; it < 4; it++) {
    const int tokbase = ((blockIdx.x * 4 + wv) * 4 + it) * 16;
    const float* er = embed + (size_t)x[tokbase + m] * 256;
    f32x4 acc[4] = {{0.f,0.f,0.f,0.f},{0.f,0.f,0.f,0.f},{0.f,0.f,0.f,0.f},{0.f,0.f,0.f,0.f}};
#pragma unroll
    for (int kap = 0; kap < 8; kap++) {
      float4 p0 = *(const float4*)(er + 32 * kap + 8 * q);
      float4 p1 = *(const float4*)(er + 32 * kap + 8 * q + 4);
      short8 af;
      af[0] = (short)bfb(p0.x); af[1] = (short)bfb(p0.y);
      af[2] = (short)bfb(p0.z); af[3] = (short)bfb(p0.w);
      af[4] = (short)bfb(p1.x); af[5] = (short)bfb(p1.y);
      af[6] = (short)bfb(p1.z); af[7] = (short)bfb(p1.w);
#pragma unroll
      for (int u = 0; u < 4; u++)
        acc[u] = __builtin_amdgcn_mfma_f32_16x16x32_bf16(af, Wf[kap][u], acc[u], 0, 0, 0);
    }
    // D: row(token) = 4q+r, col(tag) = 16u+m  (m89-verified). Softmax over tags.
#pragma unroll
    for (int r = 0; r < 4; r++) {
      float e0 = acc[0][r] + bj0, e1 = acc[1][r] + bj1;
      float e2 = acc[2][r] + bj2, e3 = acc[3][r] + bj3;
      float mr = fmaxf(fmaxf(e0, e1), fmaxf(e2, e3));
#pragma unroll
      for (int off = 1; off < 16; off <<= 1) mr = fmaxf(mr, __shfl_xor(mr, off));
      float x0 = __expf(e0 - mr), x1 = __expf(e1 - mr);
      float x2 = __expf(e2 - mr), x3 = __expf(e3 - mr);
      float sr = (x0 + x1) + (x2 + x3);
#pragma unroll
      for (int off = 1; off < 16; off <<= 1) sr += __shfl_xor(sr, off);
      float rs = 1.0f / sr;
      unsigned short* Fp = Fout + (size_t)(tokbase + 4 * q + r) * T_ + m;
      Fp[0]  = bfb(x0 * rs);
      Fp[16] = bfb(x1 * rs);
      Fp[32] = bfb(x2 * rs);
      Fp[48] = bfb(x3 * rs);
    }
  }
}

// ---------- K2 phase 1: chunk transfer matrices  X_c = prod_{l in chunk} (E^T diag(F_l)) ----
// One wave per (batch, chunk). X as MFMA B-operand (cols = chunk-input tag = lane&31).
__global__ __launch_bounds__(64) void k_scan(const unsigned short* __restrict__ F,
                                             const unsigned short* __restrict__ expET,
                                             unsigned short* __restrict__ XT,
                                             float* __restrict__ rlog,
                                             int Cshift) {
  const int job = blockIdx.x;
  const int C = 1 << Cshift;
  const int c = job & (C - 1);
  const int b = job >> Cshift;
  const int K = (1023 + C - 1) >> Cshift;
  const int a = 1 + c * K;
  const int len = min(K, 1024 - a);
  const int L = threadIdx.x, nh = L & 31, hh = L >> 5;

  // A = E^T static frags: A[m=lane&31][k=16*kap+8*hh+d]
  short8 Af[2][4];
#pragma unroll
  for (int I = 0; I < 2; I++)
#pragma unroll
    for (int kap = 0; kap < 4; kap++)
      Af[I][kap] = *(const short8*)(expET + (32 * I + nh) * T_ + 16 * kap + 8 * hh);

  // B = X = Identity (bf16)
  unsigned Bf[4][2][4];
#pragma unroll
  for (int kap = 0; kap < 4; kap++)
#pragma unroll
    for (int J = 0; J < 2; J++)
#pragma unroll
      for (int dw = 0; dw < 4; dw++) {
        int k0 = 16 * kap + 8 * hh + 2 * dw, n = 32 * J + nh;
        unsigned u = 0;
        if (k0 == n) u = 0x3F80u;
        if (k0 + 1 == n) u = 0x3F800000u;
        Bf[kap][J][dw] = u;
      }

  const unsigned short* Fb = F + (size_t)b * (L_ * T_);
  uint2 Fc[2][4];
#pragma unroll
  for (int I = 0; I < 2; I++)
#pragma unroll
    for (int j = 0; j < 4; j++)
      Fc[I][j] = *(const uint2*)(Fb + (size_t)a * T_ + (16 * I + 4 * j + 2 * hh) * 2);

  float logacc = 0.f;
  unsigned PD[2][2][4][2];

  for (int s = 0; s < len; s++) {
    // D = E^T * X   (16 MFMAs; D rows = new tag, cols = input tag)
    f32x16 D[2][2];
#pragma unroll
    for (int I = 0; I < 2; I++)
#pragma unroll
      for (int J = 0; J < 2; J++) {
        f32x16 d = {};
#pragma unroll
        for (int kap = 0; kap < 4; kap++) {
          short8 bfr = __builtin_bit_cast(short8,
              make_uint4(Bf[kap][J][0], Bf[kap][J][1], Bf[kap][J][2], Bf[kap][J][3]));
          d = __builtin_amdgcn_mfma_f32_32x32x16_bf16(Af[I][kap], bfr, d, 0, 0, 0);
        }
        D[I][J] = d;
      }
    // prefetch next step's F row
    uint2 Fn[2][4];
    {
      const int ln = (s + 1 < len) ? (a + s + 1) : (a + s);
#pragma unroll
      for (int I = 0; I < 2; I++)
#pragma unroll
        for (int j = 0; j < 4; j++)
          Fn[I][j] = *(const uint2*)(Fb + (size_t)ln * T_ + (16 * I + 4 * j + 2 * hh) * 2);
    }
    // scale D rows (row = 32I + 8j + 4hh + r, m101-verified mapping) by F_l, in place
#pragma unroll
    for (int I = 0; I < 2; I++)
#pragma unroll
      for (int j = 0; j < 4; j++) {
        uint2 g = Fc[I][j];
        float f0 = asf(g.x << 16), f1 = asf(g.x & 0xffff0000u);
        float f2 = asf(g.y << 16), f3 = asf(g.y & 0xffff0000u);
#pragma unroll
        for (int J = 0; J < 2; J++) {
          D[I][J][4 * j + 0] *= f0;
          D[I][J][4 * j + 1] *= f1;
          D[I][J][4 * j + 2] *= f2;
          D[I][J][4 * j + 3] *= f3;
        }
      }
    // periodic renorm (bound fp32/bf16 range; log tracked)
    if ((s & 7) == 7) {
      float mx = D[0][0][0];
#pragma unroll
      for (int I = 0; I < 2; I++)
#pragma unroll
        for (int J = 0; J < 2; J++)
#pragma unroll
        for (int r = 0; r < 16; r++) mx = fmaxf(mx, D[I][J][r]);
#pragma unroll
      for (int off = 1; off < 64; off <<= 1) mx = fmaxf(mx, __shfl_xor(mx, off));
      float rs = 1.0f / mx;
      logacc += __logf(mx);
#pragma unroll
      for (int I = 0; I < 2; I++)
#pragma unroll
        for (int J = 0; J < 2; J++)
#pragma unroll
        for (int r = 0; r < 16; r++) D[I][J][r] *= rs;
    }
    // pack fp32 -> bf16 dwords: PD[I][J][j][p] = rows (32I+8j+4hh+2p, +1), col 32J+nh
#pragma unroll
    for (int I = 0; I < 2; I++)
#pragma unroll
      for (int J = 0; J < 2; J++)
#pragma unroll
        for (int j = 0; j < 4; j++) {
          PD[I][J][j][0] = pk2(D[I][J][4 * j + 0], D[I][J][4 * j + 1]);
          PD[I][J][j][1] = pk2(D[I][J][4 * j + 2], D[I][J][4 * j + 3]);
        }
#pragma unroll
    for (int I = 0; I < 2; I++)
#pragma unroll
      for (int j = 0; j < 4; j++) Fc[I][j] = Fn[I][j];
    if (s + 1 < len) {
      // half-wave exchange: D 4-row groups -> B 8-row groups
      unsigned RV[2][2][4][2];
#pragma unroll
      for (int I = 0; I < 2; I++)
#pragma unroll
        for (int J = 0; J < 2; J++)
#pragma unroll
          for (int j = 0; j < 4; j++) {
            RV[I][J][j][0] = sx32(PD[I][J][j][0]);
            RV[I][J][j][1] = sx32(PD[I][J][j][1]);
          }
#pragma unroll
      for (int kap = 0; kap < 4; kap++) {
        const int Ip = kap >> 1, e2 = 2 * (kap & 1);
#pragma unroll
        for (int J = 0; J < 2; J++) {
          Bf[kap][J][0] = hh ? RV[Ip][J][e2 + 1][0] : PD[Ip][J][e2][0];
          Bf[kap][J][1] = hh ? RV[Ip][J][e2 + 1][1] : PD[Ip][J][e2][1];
          Bf[kap][J][2] = hh ? PD[Ip][J][e2 + 1][0] : RV[Ip][J][e2][0];
          Bf[kap][J][3] = hh ? PD[Ip][J][e2 + 1][1] : RV[Ip][J][e2][1];
        }
      }
    }
  }
  // write X_c transposed: XT[n][row] so phase-2 reads coalesce
  unsigned* X2 = (unsigned*)(XT + (size_t)job * 4096);
#pragma unroll
  for (int I = 0; I < 2; I++)
#pragma unroll
    for (int J = 0; J < 2; J++)
#pragma unroll
      for (int j = 0; j < 4; j++) {
        X2[(32 * J + nh) * 32 + 16 * I + 4 * j + 2 * hh + 0] = PD[I][J][j][0];
        X2[(32 * J + nh) * 32 + 16 * I + 4 * j + 2 * hh + 1] = PD[I][J][j][1];
      }
  if (L == 0) rlog[job] = logacc;
}

// ---------- K3 phase 2: sequential chunk application, one wave per batch ----------
__global__ __launch_bounds__(64) void k_apply(const unsigned short* __restrict__ XT,
                                              const float* __restrict__ rlog,
                                              const unsigned short* __restrict__ F,
                                              const float* __restrict__ trans,
                                              float* __restrict__ logz, int Cshift) {
  const int b = blockIdx.x, i = threadIdx.x;
  const int C = 1 << Cshift;
  __shared__ float vS[64];
  float v = __expf(trans[i]) * bf2f(F[(size_t)b * (L_ * T_) + i]);  // x0 = expT[S]*F0
  float lacc = 0.f;
  vS[i] = v;
  __syncthreads();
  for (int c = 0; c < C; c++) {
    const unsigned short* Xc = XT + (size_t)(b * C + c) * 4096;
    float a0 = 0.f, a1 = 0.f, a2 = 0.f, a3 = 0.f;
#pragma unroll
    for (int j = 0; j < 64; j += 4) {
      a0 = fmaf(bf2f(Xc[(j + 0) * T_ + i]), vS[j + 0], a0);
      a1 = fmaf(bf2f(Xc[(j + 1) * T_ + i]), vS[j + 1], a1);
      a2 = fmaf(bf2f(Xc[(j + 2) * T_ + i]), vS[j + 2], a2);
      a3 = fmaf(bf2f(Xc[(j + 3) * T_ + i]), vS[j + 3], a3);
    }
    float nv = (a0 + a1) + (a2 + a3);
    float mx = nv;
#pragma unroll
    for (int off = 1; off < 64; off <<= 1) mx = fmaxf(mx, __shfl_xor(mx, off));
    v = nv * (1.0f / mx);
    lacc += __logf(mx) + rlog[b * C + c];
    __syncthreads();
    vS[i] = v;
    __syncthreads();
  }
  float t = v * __expf(trans[i * T_ + 1]);
#pragma unroll
  for (int off = 1; off < 64; off <<= 1) t += __shfl_xor(t, off);
  if (i == 0) logz[b] = lacc + __logf(t);
}

// ---------- K4: gold path score (emission = log F + const, const cancels) ----------
__global__ __launch_bounds__(256) void k_scores(const int* __restrict__ tags,
                                                const unsigned short* __restrict__ F,
                                                const float* __restrict__ trans,
                                                float* __restrict__ score) {
  const int b = blockIdx.x;
  const int* tg = tags + (size_t)b * L_;
  const unsigned short* Fu = F + (size_t)b * (L_ * T_);
  float acc = 0.f;
  for (int l = threadIdx.x; l < L_; l += 256) {
    const int t = tg[l];
    acc += __logf(bf2f(Fu[(size_t)l * T_ + t]));
    if (l < L_ - 1) acc += trans[t * T_ + tg[l + 1]];
  }
#pragma unroll
  for (int off = 32; off > 0; off >>= 1) acc += __shfl_xor(acc, off);
  __shared__ float red[4];
  if ((threadIdx.x & 63) == 0) red[threadIdx.x >> 6] = acc;
  __syncthreads();
  if (threadIdx.x == 0) {
    float s = red[0] + red[1] + red[2] + red[3];
    s += trans[0 * T_ + tg[0]];
    s += trans[tg[L_ - 1] * T_ + 1];
    score[b] = s;
  }
}

// ---------- K5: out = -sum_b (score_b - logz_b) ----------
__global__ __launch_bounds__(128) void k_final(const float* __restrict__ score,
                                               const float* __restrict__ logz,
                                               float* __restrict__ out) {
  const int t = threadIdx.x;
  float v = score[t] - logz[t];
#pragma unroll
  for (int off = 32; off > 0; off >>= 1) v += __shfl_xor(v, off);
  __shared__ float r[2];
  if ((t & 63) == 0) r[t >> 6] = v;
  __syncthreads();
  if (t == 0) out[0] = -(r[0] + r[1]);
}

extern "C" void kernel_launch(void* const* d_in, const int* in_sizes, int n_in,
                              void* d_out, int out_size, void* d_ws, size_t ws_size,
                              hipStream_t stream) {
  const int* x = (const int*)d_in[0];
  const int* tags = (const int*)d_in[1];
  const float* embed = (const float*)d_in[3];
  const float* W = (const float*)d_in[4];
  const float* bias = (const float*)d_in[5];
  const float* trans = (const float*)d_in[6];

  const size_t fbytes = (size_t)B_ * L_ * T_ * 2;  // 16 MB
  int Cshift = 5;
  while (Cshift > 0) {
    size_t need = fbytes + (((size_t)1 << Cshift) * 1048576)   // XT
                  + (((size_t)128 << Cshift) * 4)              // rlog
                  + 1024 + 8192;                               // logz+score, expET
    if (need <= ws_size) break;
    Cshift--;
  }
  const int C = 1 << Cshift;

  char* ws = (char*)d_ws;
  unsigned short* F = (unsigned short*)ws;
  unsigned short* XT = (unsigned short*)(ws + fbytes);
  float* rlog = (float*)(ws + fbytes + (size_t)C * 1048576);
  float* logz = (float*)((char*)rlog + (size_t)128 * C * 4);
  float* score = logz + B_;
  unsigned short* expET = (unsigned short*)((char*)logz + 1024);
  float* out = (float*)d_out;

  k_prep<<<16, 256, 0, stream>>>(trans, expET);
  k_emis<<<512, 256, 0, stream>>>(x, embed, W, bias, F);
  k_scan<<<128 * C, 64, 0, stream>>>(F, expET, XT, rlog, Cshift);
  k_apply<<<B_, 64, 0, stream>>>(XT, rlog, F, trans, logz, Cshift);
  k_scores<<<B_, 256, 0, stream>>>(tags, F, trans, score);
  k_final<<<1, 128, 0, stream>>>(score, logz, out);
}

// Round 5
// 245.951 us; speedup vs baseline: 4.1886x; 1.0241x over previous
//
#include <hip/hip_runtime.h>
#include <hip/hip_bf16.h>

#define B_ 128
#define L_ 1024
#define T_ 64

using short8 = __attribute__((ext_vector_type(8))) short;
using f32x4  = __attribute__((ext_vector_type(4))) float;
using f32x16 = __attribute__((ext_vector_type(16))) float;

static __device__ __forceinline__ unsigned short bfb(float x) {
  return __builtin_bit_cast(unsigned short, __float2bfloat16(x));
}
static __device__ __forceinline__ float asf(unsigned u) { return __builtin_bit_cast(float, u); }
static __device__ __forceinline__ float bf2f(unsigned short b) { return asf(((unsigned)b) << 16); }
// packed 2xf32 -> bf16x2 dword (lo in low half); lowers to v_cvt_pk_bf16_f32 on gfx950
static __device__ __forceinline__ unsigned pk2(float lo, float hi) {
  __hip_bfloat162 h = __float22bfloat162_rn(float2{lo, hi});
  unsigned u;
  __builtin_memcpy(&u, &h, 4);  // bit_cast rejected: __hip_bfloat162 not trivially copyable
  return u;
}
// gfx950 half-wave exchange: x' = {x.lo, y.lo}, y' = {x.hi, y.hi} (lane-half-wise)
static __device__ __forceinline__ void pswap(unsigned& x, unsigned& y) {
  asm("v_permlane32_swap_b32 %0, %1" : "+v"(x), "+v"(y));
}

// ---------- K0: expET[i][k] = exp(trans[k][i])  (bf16, A-operand table) ----------
__global__ __launch_bounds__(256) void k_prep(const float* __restrict__ trans,
                                              unsigned short* __restrict__ expET) {
  int t = blockIdx.x * 256 + threadIdx.x;  // 4096
  expET[t] = bfb(__expf(trans[(t & 63) * T_ + (t >> 6)]));
}

// ---------- K1: F[token][tag] = softmax_tag(embed[x]·W + b)  (bf16) ----------
__global__ __launch_bounds__(256) void k_emis(const int* __restrict__ x,
                                              const float* __restrict__ embed,
                                              const float* __restrict__ W,
                                              const float* __restrict__ bias,
                                              unsigned short* __restrict__ Fout) {
  const int L = threadIdx.x & 63, wv = threadIdx.x >> 6, m = L & 15, q = L >> 4;
  // B = W fragments, held in VGPRs (no LDS restage)
  short8 Wf[8][4];
#pragma unroll
  for (int kap = 0; kap < 8; kap++)
#pragma unroll
    for (int u = 0; u < 4; u++) {
      short8 w;
#pragma unroll
      for (int d = 0; d < 8; d++)
        w[d] = (short)bfb(W[(32 * kap + 8 * q + d) * T_ + 16 * u + m]);
      Wf[kap][u] = w;
    }
  const float bj0 = bias[m], bj1 = bias[16 + m], bj2 = bias[32 + m], bj3 = bias[48 + m];
  for (int it = 0; it < 4; it++) {
    const int tokbase = ((blockIdx.x * 4 + wv) * 4 + it) * 16;
    const float* er = embed + (size_t)x[tokbase + m] * 256;
    f32x4 acc[4] = {{0.f,0.f,0.f,0.f},{0.f,0.f,0.f,0.f},{0.f,0.f,0.f,0.f},{0.f,0.f,0.f,0.f}};
#pragma unroll
    for (int kap = 0; kap < 8; kap++) {
      float4 p0 = *(const float4*)(er + 32 * kap + 8 * q);
      float4 p1 = *(const float4*)(er + 32 * kap + 8 * q + 4);
      unsigned u0 = pk2(p0.x, p0.y), u1 = pk2(p0.z, p0.w);
      unsigned u2 = pk2(p1.x, p1.y), u3 = pk2(p1.z, p1.w);
      short8 af = __builtin_bit_cast(short8, make_uint4(u0, u1, u2, u3));
#pragma unroll
      for (int u = 0; u < 4; u++)
        acc[u] = __builtin_amdgcn_mfma_f32_16x16x32_bf16(af, Wf[kap][u], acc[u], 0, 0, 0);
    }
    // D: row(token) = 4q+r, col(tag) = 16u+m. Softmax over tags.
#pragma unroll
    for (int r = 0; r < 4; r++) {
      float e0 = acc[0][r] + bj0, e1 = acc[1][r] + bj1;
      float e2 = acc[2][r] + bj2, e3 = acc[3][r] + bj3;
      float mr = fmaxf(fmaxf(e0, e1), fmaxf(e2, e3));
#pragma unroll
      for (int off = 1; off < 16; off <<= 1) mr = fmaxf(mr, __shfl_xor(mr, off));
      float x0 = __expf(e0 - mr), x1 = __expf(e1 - mr);
      float x2 = __expf(e2 - mr), x3 = __expf(e3 - mr);
      float sr = (x0 + x1) + (x2 + x3);
#pragma unroll
      for (int off = 1; off < 16; off <<= 1) sr += __shfl_xor(sr, off);
      float rs = 1.0f / sr;
      unsigned short* Fp = Fout + (size_t)(tokbase + 4 * q + r) * T_ + m;
      Fp[0]  = bfb(x0 * rs);
      Fp[16] = bfb(x1 * rs);
      Fp[32] = bfb(x2 * rs);
      Fp[48] = bfb(x3 * rs);
    }
  }
}

// ---------- K2 phase 1: chunk transfer matrices  X_c = prod_{l in chunk} (diag(F_l)·E^T) ----
// One wave per (batch, chunk). X as MFMA B-operand (cols = chunk-input tag = lane&31).
__global__ __launch_bounds__(64) void k_scan(const unsigned short* __restrict__ F,
                                             const unsigned short* __restrict__ expET,
                                             unsigned short* __restrict__ XT,
                                             float* __restrict__ rlog,
                                             int Cshift) {
  const int job = blockIdx.x;
  const int C = 1 << Cshift;
  const int c = job & (C - 1);
  const int b = job >> Cshift;
  const int K = (1023 + C - 1) >> Cshift;
  const int a = 1 + c * K;
  const int len = min(K, 1024 - a);
  const int L = threadIdx.x, nh = L & 31, hh = L >> 5;

  // A = E^T static frags: A[m=lane&31][k=16*kap+8*hh+d]
  short8 Af[2][4];
#pragma unroll
  for (int I = 0; I < 2; I++)
#pragma unroll
    for (int kap = 0; kap < 4; kap++)
      Af[I][kap] = *(const short8*)(expET + (32 * I + nh) * T_ + 16 * kap + 8 * hh);

  // B = X = Identity (bf16)
  unsigned Bf[4][2][4];
#pragma unroll
  for (int kap = 0; kap < 4; kap++)
#pragma unroll
    for (int J = 0; J < 2; J++)
#pragma unroll
      for (int dw = 0; dw < 4; dw++) {
        int k0 = 16 * kap + 8 * hh + 2 * dw, n = 32 * J + nh;
        unsigned u = 0;
        if (k0 == n) u = 0x3F80u;
        if (k0 + 1 == n) u = 0x3F800000u;
        Bf[kap][J][dw] = u;
      }

  const unsigned short* Fb = F + (size_t)b * (L_ * T_);
  uint2 Fc[2][4];
#pragma unroll
  for (int I = 0; I < 2; I++)
#pragma unroll
    for (int j = 0; j < 4; j++)
      Fc[I][j] = *(const uint2*)(Fb + (size_t)a * T_ + (16 * I + 4 * j + 2 * hh) * 2);

  float logacc = 0.f;
  unsigned PD[2][2][4][2];

  for (int s = 0; s < len; s++) {
    // D = E^T * X   (16 MFMAs; D rows = new tag, cols = input tag)
    f32x16 D[2][2];
#pragma unroll
    for (int I = 0; I < 2; I++)
#pragma unroll
      for (int J = 0; J < 2; J++) {
        f32x16 d = {};
#pragma unroll
        for (int kap = 0; kap < 4; kap++) {
          short8 bfr = __builtin_bit_cast(short8,
              make_uint4(Bf[kap][J][0], Bf[kap][J][1], Bf[kap][J][2], Bf[kap][J][3]));
          d = __builtin_amdgcn_mfma_f32_32x32x16_bf16(Af[I][kap], bfr, d, 0, 0, 0);
        }
        D[I][J] = d;
      }
    // prefetch next step's F row
    uint2 Fn[2][4];
    {
      const int ln = (s + 1 < len) ? (a + s + 1) : (a + s);
#pragma unroll
      for (int I = 0; I < 2; I++)
#pragma unroll
        for (int j = 0; j < 4; j++)
          Fn[I][j] = *(const uint2*)(Fb + (size_t)ln * T_ + (16 * I + 4 * j + 2 * hh) * 2);
    }
    // scale D rows (row = 32I + 8j + 4hh + r) by F_l, in place
#pragma unroll
    for (int I = 0; I < 2; I++)
#pragma unroll
      for (int j = 0; j < 4; j++) {
        uint2 g = Fc[I][j];
        float f0 = asf(g.x << 16), f1 = asf(g.x & 0xffff0000u);
        float f2 = asf(g.y << 16), f3 = asf(g.y & 0xffff0000u);
#pragma unroll
        for (int J = 0; J < 2; J++) {
          D[I][J][4 * j + 0] *= f0;
          D[I][J][4 * j + 1] *= f1;
          D[I][J][4 * j + 2] *= f2;
          D[I][J][4 * j + 3] *= f3;
        }
      }
    // periodic renorm (precision-scale guard; F is softmax-normalized so drift is slow)
    if ((s & 15) == 15) {
      float mx = D[0][0][0];
#pragma unroll
      for (int I = 0; I < 2; I++)
#pragma unroll
        for (int J = 0; J < 2; J++)
#pragma unroll
        for (int r = 0; r < 16; r++) mx = fmaxf(mx, D[I][J][r]);
#pragma unroll
      for (int off = 1; off < 64; off <<= 1) mx = fmaxf(mx, __shfl_xor(mx, off));
      float rs = 1.0f / mx;
      logacc += __logf(mx);
#pragma unroll
      for (int I = 0; I < 2; I++)
#pragma unroll
        for (int J = 0; J < 2; J++)
#pragma unroll
        for (int r = 0; r < 16; r++) D[I][J][r] *= rs;
    }
    // pack fp32 -> bf16 dwords: PD[I][J][j][p] = rows (32I+8j+4hh+2p, +1), col 32J+nh
#pragma unroll
    for (int I = 0; I < 2; I++)
#pragma unroll
      for (int J = 0; J < 2; J++)
#pragma unroll
        for (int j = 0; j < 4; j++) {
          PD[I][J][j][0] = pk2(D[I][J][4 * j + 0], D[I][J][4 * j + 1]);
          PD[I][J][j][1] = pk2(D[I][J][4 * j + 2], D[I][J][4 * j + 3]);
        }
#pragma unroll
    for (int I = 0; I < 2; I++)
#pragma unroll
      for (int j = 0; j < 4; j++) Fc[I][j] = Fn[I][j];
    if (s + 1 < len) {
      // half-wave exchange via v_permlane32_swap_b32:
      //   x' = {own_lo(PD[e2]), other_lo(PD[e2+1])} = Bf dword p
      //   y' = {other_hi(PD[e2]), own_hi(PD[e2+1])} = Bf dword p+2
#pragma unroll
      for (int kap = 0; kap < 4; kap++) {
        const int Ip = kap >> 1, e2 = 2 * (kap & 1);
#pragma unroll
        for (int J = 0; J < 2; J++) {
          unsigned x0 = PD[Ip][J][e2][0], y0 = PD[Ip][J][e2 + 1][0];
          unsigned x1 = PD[Ip][J][e2][1], y1 = PD[Ip][J][e2 + 1][1];
          pswap(x0, y0);
          pswap(x1, y1);
          Bf[kap][J][0] = x0;
          Bf[kap][J][1] = x1;
          Bf[kap][J][2] = y0;
          Bf[kap][J][3] = y1;
        }
      }
    }
  }
  // write X_c transposed: XT[n][row] so phase-2 reads coalesce
  unsigned* X2 = (unsigned*)(XT + (size_t)job * 4096);
#pragma unroll
  for (int I = 0; I < 2; I++)
#pragma unroll
    for (int J = 0; J < 2; J++)
#pragma unroll
      for (int j = 0; j < 4; j++) {
        X2[(32 * J + nh) * 32 + 16 * I + 4 * j + 2 * hh + 0] = PD[I][J][j][0];
        X2[(32 * J + nh) * 32 + 16 * I + 4 * j + 2 * hh + 1] = PD[I][J][j][1];
      }
  if (L == 0) rlog[job] = logacc;
}

// ---------- K3 phase 2: sequential chunk application, one wave per batch ----------
__global__ __launch_bounds__(64) void k_apply(const unsigned short* __restrict__ XT,
                                              const float* __restrict__ rlog,
                                              const unsigned short* __restrict__ F,
                                              const float* __restrict__ trans,
                                              float* __restrict__ logz, int Cshift) {
  const int b = blockIdx.x, i = threadIdx.x;
  const int C = 1 << Cshift;
  __shared__ float vS[64];
  float v = __expf(trans[i]) * bf2f(F[(size_t)b * (L_ * T_) + i]);  // x0 = expT[S]*F0
  float lacc = 0.f;
  vS[i] = v;
  __syncthreads();
  for (int c = 0; c < C; c++) {
    const unsigned short* Xc = XT + (size_t)(b * C + c) * 4096;
    float a0 = 0.f, a1 = 0.f, a2 = 0.f, a3 = 0.f;
#pragma unroll
    for (int j = 0; j < 64; j += 4) {
      a0 = fmaf(bf2f(Xc[(j + 0) * T_ + i]), vS[j + 0], a0);
      a1 = fmaf(bf2f(Xc[(j + 1) * T_ + i]), vS[j + 1], a1);
      a2 = fmaf(bf2f(Xc[(j + 2) * T_ + i]), vS[j + 2], a2);
      a3 = fmaf(bf2f(Xc[(j + 3) * T_ + i]), vS[j + 3], a3);
    }
    float nv = (a0 + a1) + (a2 + a3);
    float mx = nv;
#pragma unroll
    for (int off = 1; off < 64; off <<= 1) mx = fmaxf(mx, __shfl_xor(mx, off));
    v = nv * (1.0f / mx);
    lacc += __logf(mx) + rlog[b * C + c];
    __syncthreads();
    vS[i] = v;
    __syncthreads();
  }
  float t = v * __expf(trans[i * T_ + 1]);
#pragma unroll
  for (int off = 1; off < 64; off <<= 1) t += __shfl_xor(t, off);
  if (i == 0) logz[b] = lacc + __logf(t);
}

// ---------- K4: gold path score (emission = log F + const, const cancels) ----------
__global__ __launch_bounds__(256) void k_scores(const int* __restrict__ tags,
                                                const unsigned short* __restrict__ F,
                                                const float* __restrict__ trans,
                                                float* __restrict__ score) {
  const int b = blockIdx.x;
  const int* tg = tags + (size_t)b * L_;
  const unsigned short* Fu = F + (size_t)b * (L_ * T_);
  float acc = 0.f;
  for (int l = threadIdx.x; l < L_; l += 256) {
    const int t = tg[l];
    acc += __logf(bf2f(Fu[(size_t)l * T_ + t]));
    if (l < L_ - 1) acc += trans[t * T_ + tg[l + 1]];
  }
#pragma unroll
  for (int off = 32; off > 0; off >>= 1) acc += __shfl_xor(acc, off);
  __shared__ float red[4];
  if ((threadIdx.x & 63) == 0) red[threadIdx.x >> 6] = acc;
  __syncthreads();
  if (threadIdx.x == 0) {
    float s = red[0] + red[1] + red[2] + red[3];
    s += trans[0 * T_ + tg[0]];
    s += trans[tg[L_ - 1] * T_ + 1];
    score[b] = s;
  }
}

// ---------- K5: out = -sum_b (score_b - logz_b) ----------
__global__ __launch_bounds__(128) void k_final(const float* __restrict__ score,
                                               const float* __restrict__ logz,
                                               float* __restrict__ out) {
  const int t = threadIdx.x;
  float v = score[t] - logz[t];
#pragma unroll
  for (int off = 32; off > 0; off >>= 1) v += __shfl_xor(v, off);
  __shared__ float r[2];
  if ((t & 63) == 0) r[t >> 6] = v;
  __syncthreads();
  if (t == 0) out[0] = -(r[0] + r[1]);
}

extern "C" void kernel_launch(void* const* d_in, const int* in_sizes, int n_in,
                              void* d_out, int out_size, void* d_ws, size_t ws_size,
                              hipStream_t stream) {
  const int* x = (const int*)d_in[0];
  const int* tags = (const int*)d_in[1];
  const float* embed = (const float*)d_in[3];
  const float* W = (const float*)d_in[4];
  const float* bias = (const float*)d_in[5];
  const float* trans = (const float*)d_in[6];

  const size_t fbytes = (size_t)B_ * L_ * T_ * 2;  // 16 MB
  int Cshift = 5;
  while (Cshift > 0) {
    size_t need = fbytes + (((size_t)1 << Cshift) * 1048576)   // XT
                  + (((size_t)128 << Cshift) * 4)              // rlog
                  + 1024 + 8192;                               // logz+score, expET
    if (need <= ws_size) break;
    Cshift--;
  }
  const int C = 1 << Cshift;

  char* ws = (char*)d_ws;
  unsigned short* F = (unsigned short*)ws;
  unsigned short* XT = (unsigned short*)(ws + fbytes);
  float* rlog = (float*)(ws + fbytes + (size_t)C * 1048576);
  float* logz = (float*)((char*)rlog + (size_t)128 * C * 4);
  float* score = logz + B_;
  unsigned short* expET = (unsigned short*)((char*)logz + 1024);
  float* out = (float*)d_out;

  k_prep<<<16, 256, 0, stream>>>(trans, expET);
  k_emis<<<512, 256, 0, stream>>>(x, embed, W, bias, F);
  k_scan<<<128 * C, 64, 0, stream>>>(F, expET, XT, rlog, Cshift);
  k_apply<<<B_, 64, 0, stream>>>(XT, rlog, F, trans, logz, Cshift);
  k_scores<<<B_, 256, 0, stream>>>(tags, F, trans, score);
  k_final<<<1, 128, 0, stream>>>(score, logz, out);
}

// Round 8
// 233.727 us; speedup vs baseline: 4.4077x; 1.0523x over previous
//
#include <hip/hip_runtime.h>
#include <hip/hip_bf16.h>

#define B_ 128
#define L_ 1024
#define T_ 64

using short8 = __attribute__((ext_vector_type(8))) short;
using f32x4  = __attribute__((ext_vector_type(4))) float;
using f32x16 = __attribute__((ext_vector_type(16))) float;

static __device__ __forceinline__ unsigned short bfb(float x) {
  return __builtin_bit_cast(unsigned short, __float2bfloat16(x));
}
static __device__ __forceinline__ float asf(unsigned u) { return __builtin_bit_cast(float, u); }
static __device__ __forceinline__ float bf2f(unsigned short b) { return asf(((unsigned)b) << 16); }
// packed 2xf32 -> bf16x2 dword via RNE (verified r5)
static __device__ __forceinline__ unsigned pk2(float lo, float hi) {
  __hip_bfloat162 h = __float22bfloat162_rn(float2{lo, hi});
  unsigned u;
  __builtin_memcpy(&u, &h, 4);
  return u;
}
// packed 2xf32 -> bf16x2 dword by TRUNCATION: one v_perm_b32 (positive, well-scaled data)
static __device__ __forceinline__ unsigned pk2t(float lo, float hi) {
  return __builtin_amdgcn_perm(__builtin_bit_cast(unsigned, hi),
                               __builtin_bit_cast(unsigned, lo), 0x07060302u);
}
// gfx950 half-wave exchange: x' = {x.lo, y.lo}, y' = {x.hi, y.hi} (lane-half-wise)
static __device__ __forceinline__ void pswap(unsigned& x, unsigned& y) {
  asm("v_permlane32_swap_b32 %0, %1" : "+v"(x), "+v"(y));
}

// ---------- K0: expET[i][k] = exp(trans[k][i])  (bf16, A-operand table) ----------
__global__ __launch_bounds__(256) void k_prep(const float* __restrict__ trans,
                                              unsigned short* __restrict__ expET) {
  int t = blockIdx.x * 256 + threadIdx.x;  // 4096
  expET[t] = bfb(__expf(trans[(t & 63) * T_ + (t >> 6)]));
}

// ---------- K1: F[token][tag] = softmax_tag(embed[x]·W + b)  (bf16) ----------
__global__ __launch_bounds__(256) void k_emis(const int* __restrict__ x,
                                              const float* __restrict__ embed,
                                              const float* __restrict__ W,
                                              const float* __restrict__ bias,
                                              unsigned short* __restrict__ Fout) {
  const int L = threadIdx.x & 63, wv = threadIdx.x >> 6, m = L & 15, q = L >> 4;
  // B = W fragments, held in VGPRs (no LDS restage)
  short8 Wf[8][4];
#pragma unroll
  for (int kap = 0; kap < 8; kap++)
#pragma unroll
    for (int u = 0; u < 4; u++) {
      short8 w;
#pragma unroll
      for (int d = 0; d < 8; d++)
        w[d] = (short)bfb(W[(32 * kap + 8 * q + d) * T_ + 16 * u + m]);
      Wf[kap][u] = w;
    }
  const float bj0 = bias[m], bj1 = bias[16 + m], bj2 = bias[32 + m], bj3 = bias[48 + m];
  for (int it = 0; it < 4; it++) {
    const int tokbase = ((blockIdx.x * 4 + wv) * 4 + it) * 16;
    const float* er = embed + (size_t)x[tokbase + m] * 256;
    f32x4 acc[4] = {{0.f,0.f,0.f,0.f},{0.f,0.f,0.f,0.f},{0.f,0.f,0.f,0.f},{0.f,0.f,0.f,0.f}};
#pragma unroll
    for (int kap = 0; kap < 8; kap++) {
      float4 p0 = *(const float4*)(er + 32 * kap + 8 * q);
      float4 p1 = *(const float4*)(er + 32 * kap + 8 * q + 4);
      unsigned u0 = pk2(p0.x, p0.y), u1 = pk2(p0.z, p0.w);
      unsigned u2 = pk2(p1.x, p1.y), u3 = pk2(p1.z, p1.w);
      short8 af = __builtin_bit_cast(short8, make_uint4(u0, u1, u2, u3));
#pragma unroll
      for (int u = 0; u < 4; u++)
        acc[u] = __builtin_amdgcn_mfma_f32_16x16x32_bf16(af, Wf[kap][u], acc[u], 0, 0, 0);
    }
    // D: row(token) = 4q+r, col(tag) = 16u+m. Softmax over tags.
#pragma unroll
    for (int r = 0; r < 4; r++) {
      float e0 = acc[0][r] + bj0, e1 = acc[1][r] + bj1;
      float e2 = acc[2][r] + bj2, e3 = acc[3][r] + bj3;
      float mr = fmaxf(fmaxf(e0, e1), fmaxf(e2, e3));
#pragma unroll
      for (int off = 1; off < 16; off <<= 1) mr = fmaxf(mr, __shfl_xor(mr, off));
      float x0 = __expf(e0 - mr), x1 = __expf(e1 - mr);
      float x2 = __expf(e2 - mr), x3 = __expf(e3 - mr);
      float sr = (x0 + x1) + (x2 + x3);
#pragma unroll
      for (int off = 1; off < 16; off <<= 1) sr += __shfl_xor(sr, off);
      float rs = 1.0f / sr;
      unsigned short* Fp = Fout + (size_t)(tokbase + 4 * q + r) * T_ + m;
      Fp[0]  = bfb(x0 * rs);
      Fp[16] = bfb(x1 * rs);
      Fp[32] = bfb(x2 * rs);
      Fp[48] = bfb(x3 * rs);
    }
  }
}

// ---------- K2 phase 1: chunk transfer matrices  X_c = prod_{l in chunk} (diag(F_l)·E^T) ----
// One wave per (batch, chunk). X as MFMA B-operand (cols = chunk-input tag = lane&31).
__global__ __launch_bounds__(64) void k_scan(const unsigned short* __restrict__ F,
                                             const unsigned short* __restrict__ expET,
                                             unsigned short* __restrict__ XT,
                                             float* __restrict__ rlog,
                                             int Cshift) {
  const int job = blockIdx.x;
  const int C = 1 << Cshift;
  const int c = job & (C - 1);
  const int b = job >> Cshift;
  const int K = (1023 + C - 1) >> Cshift;
  const int a = 1 + c * K;
  const int len = min(K, 1024 - a);
  const int L = threadIdx.x, nh = L & 31, hh = L >> 5;

  // A = E^T static frags: A[m=lane&31][k=16*kap+8*hh+d]
  short8 Af[2][4];
#pragma unroll
  for (int I = 0; I < 2; I++)
#pragma unroll
    for (int kap = 0; kap < 4; kap++)
      Af[I][kap] = *(const short8*)(expET + (32 * I + nh) * T_ + 16 * kap + 8 * hh);

  // B = X = Identity (bf16)
  unsigned Bf[4][2][4];
#pragma unroll
  for (int kap = 0; kap < 4; kap++)
#pragma unroll
    for (int J = 0; J < 2; J++)
#pragma unroll
      for (int dw = 0; dw < 4; dw++) {
        int k0 = 16 * kap + 8 * hh + 2 * dw, n = 32 * J + nh;
        unsigned u = 0;
        if (k0 == n) u = 0x3F80u;
        if (k0 + 1 == n) u = 0x3F800000u;
        Bf[kap][J][dw] = u;
      }

  const unsigned short* Fb = F + (size_t)b * (L_ * T_);
  uint2 Fc[2][4];
#pragma unroll
  for (int I = 0; I < 2; I++)
#pragma unroll
    for (int j = 0; j < 4; j++)
      Fc[I][j] = *(const uint2*)(Fb + (size_t)a * T_ + (16 * I + 4 * j + 2 * hh) * 2);

  float logacc = 0.f;
  unsigned PD[2][2][4][2];
  const f32x16 Z = {};  // loop-invariant zero C operand: no per-step acc re-zeroing

  for (int s = 0; s < len; s++) {
    // D = E^T * X   (16 MFMAs; D rows = new tag, cols = input tag)
    f32x16 D[2][2];
#pragma unroll
    for (int I = 0; I < 2; I++)
#pragma unroll
      for (int J = 0; J < 2; J++) {
        short8 b0 = __builtin_bit_cast(short8,
            make_uint4(Bf[0][J][0], Bf[0][J][1], Bf[0][J][2], Bf[0][J][3]));
        f32x16 d = __builtin_amdgcn_mfma_f32_32x32x16_bf16(Af[I][0], b0, Z, 0, 0, 0);
#pragma unroll
        for (int kap = 1; kap < 4; kap++) {
          short8 bk = __builtin_bit_cast(short8,
              make_uint4(Bf[kap][J][0], Bf[kap][J][1], Bf[kap][J][2], Bf[kap][J][3]));
          d = __builtin_amdgcn_mfma_f32_32x32x16_bf16(Af[I][kap], bk, d, 0, 0, 0);
        }
        D[I][J] = d;
      }
    // prefetch next step's F row
    uint2 Fn[2][4];
    {
      const int ln = (s + 1 < len) ? (a + s + 1) : (a + s);
#pragma unroll
      for (int I = 0; I < 2; I++)
#pragma unroll
        for (int j = 0; j < 4; j++)
          Fn[I][j] = *(const uint2*)(Fb + (size_t)ln * T_ + (16 * I + 4 * j + 2 * hh) * 2);
    }
    // scale D rows (row = 32I + 8j + 4hh + r) by F_l, in place
#pragma unroll
    for (int I = 0; I < 2; I++)
#pragma unroll
      for (int j = 0; j < 4; j++) {
        uint2 g = Fc[I][j];
        float f0 = asf(g.x << 16), f1 = asf(g.x & 0xffff0000u);
        float f2 = asf(g.y << 16), f3 = asf(g.y & 0xffff0000u);
#pragma unroll
        for (int J = 0; J < 2; J++) {
          D[I][J][4 * j + 0] *= f0;
          D[I][J][4 * j + 1] *= f1;
          D[I][J][4 * j + 2] *= f2;
          D[I][J][4 * j + 3] *= f3;
        }
      }
    // periodic renorm (precision-scale guard; passed in r5)
    if ((s & 15) == 15) {
      float mx = D[0][0][0];
#pragma unroll
      for (int I = 0; I < 2; I++)
#pragma unroll
        for (int J = 0; J < 2; J++)
#pragma unroll
        for (int r = 0; r < 16; r++) mx = fmaxf(mx, D[I][J][r]);
#pragma unroll
      for (int off = 1; off < 64; off <<= 1) mx = fmaxf(mx, __shfl_xor(mx, off));
      float rs = 1.0f / mx;
      logacc += __logf(mx);
#pragma unroll
      for (int I = 0; I < 2; I++)
#pragma unroll
        for (int J = 0; J < 2; J++)
#pragma unroll
        for (int r = 0; r < 16; r++) D[I][J][r] *= rs;
    }
    // pack fp32 -> bf16 dwords by truncation: PD[I][J][j][p] = rows (32I+8j+4hh+2p, +1)
#pragma unroll
    for (int I = 0; I < 2; I++)
#pragma unroll
      for (int J = 0; J < 2; J++)
#pragma unroll
        for (int j = 0; j < 4; j++) {
          PD[I][J][j][0] = pk2t(D[I][J][4 * j + 0], D[I][J][4 * j + 1]);
          PD[I][J][j][1] = pk2t(D[I][J][4 * j + 2], D[I][J][4 * j + 3]);
        }
#pragma unroll
    for (int I = 0; I < 2; I++)
#pragma unroll
      for (int j = 0; j < 4; j++) Fc[I][j] = Fn[I][j];
    if (s + 1 < len) {
      // half-wave exchange via v_permlane32_swap_b32 (verified r5)
#pragma unroll
      for (int kap = 0; kap < 4; kap++) {
        const int Ip = kap >> 1, e2 = 2 * (kap & 1);
#pragma unroll
        for (int J = 0; J < 2; J++) {
          unsigned x0 = PD[Ip][J][e2][0], y0 = PD[Ip][J][e2 + 1][0];
          unsigned x1 = PD[Ip][J][e2][1], y1 = PD[Ip][J][e2 + 1][1];
          pswap(x0, y0);
          pswap(x1, y1);
          Bf[kap][J][0] = x0;
          Bf[kap][J][1] = x1;
          Bf[kap][J][2] = y0;
          Bf[kap][J][3] = y1;
        }
      }
    }
  }
  // write X_c transposed: XT[n][row] so phase-2 reads coalesce
  unsigned* X2 = (unsigned*)(XT + (size_t)job * 4096);
#pragma unroll
  for (int I = 0; I < 2; I++)
#pragma unroll
    for (int J = 0; J < 2; J++)
#pragma unroll
      for (int j = 0; j < 4; j++) {
        X2[(32 * J + nh) * 32 + 16 * I + 4 * j + 2 * hh + 0] = PD[I][J][j][0];
        X2[(32 * J + nh) * 32 + 16 * I + 4 * j + 2 * hh + 1] = PD[I][J][j][1];
      }
  if (L == 0) rlog[job] = logacc;
}

// ---------- K3 phase 2: sequential chunk application, one wave per batch ----------
__global__ __launch_bounds__(64) void k_apply(const unsigned short* __restrict__ XT,
                                              const float* __restrict__ rlog,
                                              const unsigned short* __restrict__ F,
                                              const float* __restrict__ trans,
                                              float* __restrict__ logz, int Cshift) {
  const int b = blockIdx.x, i = threadIdx.x;
  const int C = 1 << Cshift;
  __shared__ float vS[64];
  float v = __expf(trans[i]) * bf2f(F[(size_t)b * (L_ * T_) + i]);  // x0 = expT[S]*F0
  float lacc = 0.f;
  vS[i] = v;
  __syncthreads();
  for (int c = 0; c < C; c++) {
    const unsigned short* Xc = XT + (size_t)(b * C + c) * 4096;
    float a0 = 0.f, a1 = 0.f, a2 = 0.f, a3 = 0.f;
#pragma unroll
    for (int j = 0; j < 64; j += 4) {
      a0 = fmaf(bf2f(Xc[(j + 0) * T_ + i]), vS[j + 0], a0);
      a1 = fmaf(bf2f(Xc[(j + 1) * T_ + i]), vS[j + 1], a1);
      a2 = fmaf(bf2f(Xc[(j + 2) * T_ + i]), vS[j + 2], a2);
      a3 = fmaf(bf2f(Xc[(j + 3) * T_ + i]), vS[j + 3], a3);
    }
    float nv = (a0 + a1) + (a2 + a3);
    float mx = nv;
#pragma unroll
    for (int off = 1; off < 64; off <<= 1) mx = fmaxf(mx, __shfl_xor(mx, off));
    v = nv * (1.0f / mx);
    lacc += __logf(mx) + rlog[b * C + c];
    __syncthreads();
    vS[i] = v;
    __syncthreads();
  }
  float t = v * __expf(trans[i * T_ + 1]);
#pragma unroll
  for (int off = 1; off < 64; off <<= 1) t += __shfl_xor(t, off);
  if (i == 0) logz[b] = lacc + __logf(t);
}

// ---------- K4: gold path score (emission = log F + const, const cancels) ----------
__global__ __launch_bounds__(256) void k_scores(const int* __restrict__ tags,
                                                const unsigned short* __restrict__ F,
                                                const float* __restrict__ trans,
                                                float* __restrict__ score) {
  const int b = blockIdx.x;
  const int* tg = tags + (size_t)b * L_;
  const unsigned short* Fu = F + (size_t)b * (L_ * T_);
  float acc = 0.f;
  for (int l = threadIdx.x; l < L_; l += 256) {
    const int t = tg[l];
    acc += __logf(bf2f(Fu[(size_t)l * T_ + t]));
    if (l < L_ - 1) acc += trans[t * T_ + tg[l + 1]];
  }
#pragma unroll
  for (int off = 32; off > 0; off >>= 1) acc += __shfl_xor(acc, off);
  __shared__ float red[4];
  if ((threadIdx.x & 63) == 0) red[threadIdx.x >> 6] = acc;
  __syncthreads();
  if (threadIdx.x == 0) {
    float s = red[0] + red[1] + red[2] + red[3];
    s += trans[0 * T_ + tg[0]];
    s += trans[tg[L_ - 1] * T_ + 1];
    score[b] = s;
  }
}

// ---------- K5: out = -sum_b (score_b - logz_b) ----------
__global__ __launch_bounds__(128) void k_final(const float* __restrict__ score,
                                               const float* __restrict__ logz,
                                               float* __restrict__ out) {
  const int t = threadIdx.x;
  float v = score[t] - logz[t];
#pragma unroll
  for (int off = 32; off > 0; off >>= 1) v += __shfl_xor(v, off);
  __shared__ float r[2];
  if ((t & 63) == 0) r[t >> 6] = v;
  __syncthreads();
  if (t == 0) out[0] = -(r[0] + r[1]);
}

extern "C" void kernel_launch(void* const* d_in, const int* in_sizes, int n_in,
                              void* d_out, int out_size, void* d_ws, size_t ws_size,
                              hipStream_t stream) {
  const int* x = (const int*)d_in[0];
  const int* tags = (const int*)d_in[1];
  const float* embed = (const float*)d_in[3];
  const float* W = (const float*)d_in[4];
  const float* bias = (const float*)d_in[5];
  const float* trans = (const float*)d_in[6];

  const size_t fbytes = (size_t)B_ * L_ * T_ * 2;  // 16 MB
  int Cshift = 5;
  while (Cshift > 0) {
    size_t need = fbytes + (((size_t)1 << Cshift) * 1048576)   // XT
                  + (((size_t)128 << Cshift) * 4)              // rlog
                  + 1024 + 8192;                               // logz+score, expET
    if (need <= ws_size) break;
    Cshift--;
  }
  const int C = 1 << Cshift;

  char* ws = (char*)d_ws;
  unsigned short* F = (unsigned short*)ws;
  unsigned short* XT = (unsigned short*)(ws + fbytes);
  float* rlog = (float*)(ws + fbytes + (size_t)C * 1048576);
  float* logz = (float*)((char*)rlog + (size_t)128 * C * 4);
  float* score = logz + B_;
  unsigned short* expET = (unsigned short*)((char*)logz + 1024);
  float* out = (float*)d_out;

  k_prep<<<16, 256, 0, stream>>>(trans, expET);
  k_emis<<<512, 256, 0, stream>>>(x, embed, W, bias, F);
  k_scan<<<128 * C, 64, 0, stream>>>(F, expET, XT, rlog, Cshift);
  k_apply<<<B_, 64, 0, stream>>>(XT, rlog, F, trans, logz, Cshift);
  k_scores<<<B_, 256, 0, stream>>>(tags, F, trans, score);
  k_final<<<1, 128, 0, stream>>>(score, logz, out);
}